// Round 5
// baseline (135.102 us; speedup 1.0000x reference)
//
#include <hip/hip_runtime.h>
#include <hip/hip_fp16.h>

typedef __attribute__((ext_vector_type(8))) short bf16x8;
typedef __attribute__((ext_vector_type(4))) float f32x4;

__device__ __forceinline__ unsigned short f2bf(float f) {
  unsigned u = __builtin_bit_cast(unsigned, f);
  u += 0x7fffu + ((u >> 16) & 1u);   // round-to-nearest-even
  return (unsigned short)(u >> 16);
}
__device__ __forceinline__ float bf2f(unsigned short s) {
  unsigned u = (unsigned)s << 16;
  return __builtin_bit_cast(float, u);
}
__device__ __forceinline__ unsigned short f2h(float f) {
  __half h = __float2half(f);
  return __builtin_bit_cast(unsigned short, h);
}
__device__ __forceinline__ float h2f(unsigned short bits) {
  __half h = __builtin_bit_cast(__half, bits);
  return __half2float(h);
}

// ---------------------------------------------------------------------------
// Kernel A: prep. blocks 0..511: x NCHW fp32 -> NHWC bf16.
// blocks 512..871: repack main_w -> wt[k][128][64], offset_w -> wot[k][32][64].
// ---------------------------------------------------------------------------
__global__ __launch_bounds__(256) void prep_all(
    const float* __restrict__ x, const float* __restrict__ mw,
    const float* __restrict__ ow, unsigned short* __restrict__ xt,
    unsigned short* __restrict__ wt, unsigned short* __restrict__ wot) {
  __shared__ float tile[64 * 129];
  int blk = blockIdx.x;
  int t = threadIdx.x;
  if (blk < 512) {
    const float* xrow = x + ((long)(blk >> 7) << 20) + ((blk & 127) << 7);
#pragma unroll
    for (int i = 0; i < 32; ++i) {
      int idx = t + (i << 8);          // c = idx>>7, w = idx&127
      tile[(idx >> 7) * 129 + (idx & 127)] =
          xrow[((long)(idx >> 7) << 14) + (idx & 127)];
    }
    __syncthreads();
    unsigned short* orow = xt + ((long)blk << 13);
#pragma unroll
    for (int i = 0; i < 32; ++i) {
      int idx = t + (i << 8);          // w = idx>>6, c = idx&63
      orow[idx] = f2bf(tile[(idx & 63) * 129 + (idx >> 6)]);
    }
  } else {
    int idx = (blk - 512) * 256 + t;   // 0..92159
    if (idx < 73728) {
      int c = idx & 63;
      int o = (idx >> 6) & 127;
      int k = idx >> 13;
      wt[idx] = f2bf(mw[o * 576 + c * 9 + k]);
    } else {
      int i2 = idx - 73728;
      int c = i2 & 63;
      int o = (i2 >> 6) & 31;
      int k = i2 >> 11;
      wot[i2] = (o < 18) ? f2bf(ow[o * 576 + c * 9 + k]) : (unsigned short)0;
    }
  }
}

// ---------------------------------------------------------------------------
// Kernel B: fused offset-conv + deformable conv, all MFMA.
// Block = 32-px tile x 128 out-ch, 4 waves, grid 2048 (8 blocks/CU).
// Phase 0: offsets for own 32 px via MFMA mini-GEMM (M=32pad,K=576,N=32),
//          one (m,n) fragment per wave -> offs_lds.
// Phase 1: sampling table wtab (9 taps x 32 px).
// Phase 2: per tap: shared bilinear gather -> vlds (double-buffered),
//          MFMA 16x16x32 bf16; wave = (o-half, px-half).
// LDS: 4.6K wtab + 9.2K vlds + 2.3K offs = 16.1 KB.
// ---------------------------------------------------------------------------
__global__ __launch_bounds__(256) void deform_fused(
    const unsigned short* __restrict__ xt, const unsigned short* __restrict__ wt,
    const unsigned short* __restrict__ wot, const float* __restrict__ ob,
    const float* __restrict__ mb, float* __restrict__ out) {
  __shared__ uint4 wtab[9][32];
  __shared__ unsigned short vlds[2][32 * 72];
  __shared__ float offs_lds[18][32];

  int l = blockIdx.x;
  int bid = ((l & 7) << 8) + (l >> 3);   // XCD swizzle: 256 consecutive bids/XCD
  int tile = bid & 3;
  int h = (bid >> 2) & 127;
  int b = bid >> 9;
  int w0 = tile << 5;
  int t = threadIdx.x;
  int lane = t & 63;
  int wv = t >> 6;
  int l15 = lane & 15;
  int l4 = lane >> 4;                    // 0..3
  int l4k = l4 << 3;

  const unsigned short* xb = xt + ((long)b << 20);

  // ---- Phase 0: offset mini-GEMM. wave wv -> (m-frag wv>>1, n-frag wv&1) ----
  {
    int mf = wv >> 1;
    int nf = wv & 1;
    f32x4 oacc = f32x4{0.f, 0.f, 0.f, 0.f};
#pragma unroll 1
    for (int k = 0; k < 9; ++k) {
      int ky = k / 3, kx = k - 3 * ky;
      int y = h + ky - 1;
      bool yok = (unsigned)y < 128u;
      int yc = min(max(y, 0), 127);
      const unsigned short* xrow = xb + ((long)yc << 13);
      int px = w0 + (nf << 4) + l15 + kx - 1;
      bool pv = yok && ((unsigned)px < 128u);
      int pxo = min(max(px, 0), 127) << 6;
      const unsigned short* wk = wot + (((k << 5) + (mf << 4) + l15) << 6) + l4k;
#pragma unroll
      for (int c0 = 0; c0 < 64; c0 += 32) {
        bf16x8 af = *(const bf16x8*)(wk + c0);
        bf16x8 bv = *(const bf16x8*)(xrow + pxo + c0 + l4k);
        if (!pv) bv = bf16x8{0, 0, 0, 0, 0, 0, 0, 0};
        oacc = __builtin_amdgcn_mfma_f32_16x16x32_bf16(af, bv, oacc, 0, 0, 0);
      }
    }
#pragma unroll
    for (int r = 0; r < 4; ++r) {
      int oc = (mf << 4) + (l4 << 2) + r;
      if (oc < 18)
        offs_lds[oc][(nf << 4) + l15] = oacc[r] + ob[oc];
    }
  }
  __syncthreads();   // offs_lds ready

  // ---- Phase 1: sampling table (288 = 9 taps x 32 px) ----
  for (int idx = t; idx < 288; idx += 256) {
    int px = idx & 31, k = idx >> 5;
    int ky = k / 3, kx = k - 3 * ky;
    float dy = offs_lds[2 * k][px];
    float dx = offs_lds[2 * k + 1][px];
    float py = (float)(h - 1 + ky) + dy;
    float pxf = (float)(w0 + px - 1 + kx) + dx;
    float fy = floorf(py), fx = floorf(pxf);
    float wy = py - fy, wx = pxf - fx;
    int y0 = (int)fy, x0 = (int)fx;
    int y1 = y0 + 1, x1 = x0 + 1;
    bool vy0 = (unsigned)y0 < 128u, vy1 = (unsigned)y1 < 128u;
    bool vx0 = (unsigned)x0 < 128u, vx1 = (unsigned)x1 < 128u;
    float w00 = (vy0 && vx0) ? (1.f - wy) * (1.f - wx) : 0.f;
    float w01 = (vy0 && vx1) ? (1.f - wy) * wx : 0.f;
    float w10 = (vy1 && vx0) ? wy * (1.f - wx) : 0.f;
    float w11 = (vy1 && vx1) ? wy * wx : 0.f;
    int y0c = min(max(y0, 0), 127), y1c = min(max(y1, 0), 127);
    int x0c = min(max(x0, 0), 127), x1c = min(max(x1, 0), 127);
    wtab[k][px] = make_uint4(
        (unsigned)f2h(w00) | ((unsigned)f2h(w01) << 16),
        (unsigned)f2h(w10) | ((unsigned)f2h(w11) << 16),
        (unsigned)(unsigned short)y0c | ((unsigned)(unsigned short)y1c << 16),
        (unsigned)(unsigned short)x0c | ((unsigned)(unsigned short)x1c << 16));
  }

  // mfma identity for phase 2
  int wo = (wv & 1) << 6;                // o base: 0 / 64
  int wp = (wv >> 1) << 4;               // px base: 0 / 16

  f32x4 acc[4];
#pragma unroll
  for (int m = 0; m < 4; ++m) acc[m] = f32x4{0.f, 0.f, 0.f, 0.f};

  // one gather unit per thread: px = t>>3, c-chunk = t&7
  int spx = t >> 3;
  int sco = (t & 7) << 3;
  auto sample = [&](int k, unsigned short* buf) {
    uint4 e = wtab[k][spx];
    float w00 = h2f((unsigned short)(e.x & 0xffff));
    float w01 = h2f((unsigned short)(e.x >> 16));
    float w10 = h2f((unsigned short)(e.y & 0xffff));
    float w11 = h2f((unsigned short)(e.y >> 16));
    int y0 = (int)(short)(e.z & 0xffff), y1 = (int)(short)(e.z >> 16);
    int x0 = (int)(short)(e.w & 0xffff), x1 = (int)(short)(e.w >> 16);
    const unsigned short* r0 = xb + (y0 << 13) + sco;
    const unsigned short* r1 = xb + (y1 << 13) + sco;
    bf16x8 a00 = *(const bf16x8*)(r0 + (x0 << 6));
    bf16x8 a01 = *(const bf16x8*)(r0 + (x1 << 6));
    bf16x8 a10 = *(const bf16x8*)(r1 + (x0 << 6));
    bf16x8 a11 = *(const bf16x8*)(r1 + (x1 << 6));
    unsigned rr[4];
#pragma unroll
    for (int j = 0; j < 4; ++j) {
      float v0 = w00 * bf2f((unsigned short)a00[2 * j]) +
                 w01 * bf2f((unsigned short)a01[2 * j]) +
                 w10 * bf2f((unsigned short)a10[2 * j]) +
                 w11 * bf2f((unsigned short)a11[2 * j]);
      float v1 = w00 * bf2f((unsigned short)a00[2 * j + 1]) +
                 w01 * bf2f((unsigned short)a01[2 * j + 1]) +
                 w10 * bf2f((unsigned short)a10[2 * j + 1]) +
                 w11 * bf2f((unsigned short)a11[2 * j + 1]);
      rr[j] = (unsigned)f2bf(v0) | ((unsigned)f2bf(v1) << 16);
    }
    *(uint4*)&buf[spx * 72 + sco] = make_uint4(rr[0], rr[1], rr[2], rr[3]);
  };

  __syncthreads();          // wtab ready
  sample(0, vlds[0]);
  __syncthreads();          // buf0 ready

#pragma unroll 1
  for (int k = 0; k < 9; ++k) {
    const unsigned short* buf = vlds[k & 1];
    if (k < 8) sample(k + 1, vlds[(k + 1) & 1]);   // overlap with MFMA below

    const unsigned short* wk = wt + (((k << 7) + wo + l15) << 6) + l4k;
#pragma unroll
    for (int c0 = 0; c0 < 64; c0 += 32) {
      bf16x8 af[4];
#pragma unroll
      for (int m = 0; m < 4; ++m)
        af[m] = *(const bf16x8*)(wk + c0 + (m << 10));
      bf16x8 bfr = *(const bf16x8*)&buf[(wp + l15) * 72 + c0 + l4k];
#pragma unroll
      for (int m = 0; m < 4; ++m)
        acc[m] = __builtin_amdgcn_mfma_f32_16x16x32_bf16(af[m], bfr, acc[m], 0, 0, 0);
    }
    __syncthreads();        // buffer consumed / next ready
  }

  // ---- epilogue: D row = o (lane>>4)*4+reg, col = px (lane&15) ----
  int hw0 = (h << 7) + w0;
#pragma unroll
  for (int m = 0; m < 4; ++m) {
    int orow = wo + (m << 4) + (l4 << 2);
#pragma unroll
    for (int r = 0; r < 4; ++r)
      out[((long)(b * 128 + orow + r) << 14) + hw0 + wp + l15] =
          acc[m][r] + mb[orow + r];
  }
}

extern "C" void kernel_launch(void* const* d_in, const int* in_sizes, int n_in,
                              void* d_out, int out_size, void* d_ws, size_t ws_size,
                              hipStream_t stream) {
  const float* x  = (const float*)d_in[0];
  const float* ow = (const float*)d_in[1];
  const float* ob = (const float*)d_in[2];
  const float* mw = (const float*)d_in[3];
  const float* mb = (const float*)d_in[4];
  float* out  = (float*)d_out;
  unsigned short* xt  = (unsigned short*)d_ws;                      // 8 MB
  unsigned short* wt  = (unsigned short*)((char*)d_ws + 8388608);   // 144 KB
  unsigned short* wot = (unsigned short*)((char*)d_ws + 8536064);   // 36 KB

  prep_all<<<872, 256, 0, stream>>>(x, mw, ow, xt, wt, wot);
  deform_fused<<<2048, 256, 0, stream>>>(xt, wt, wot, ob, mb, out);
}

// Round 6
// 134.257 us; speedup vs baseline: 1.0063x; 1.0063x over previous
//
#include <hip/hip_runtime.h>
#include <hip/hip_fp16.h>

typedef __attribute__((ext_vector_type(8))) short bf16x8;
typedef __attribute__((ext_vector_type(4))) float f32x4;

__device__ __forceinline__ unsigned short f2bf(float f) {
  unsigned u = __builtin_bit_cast(unsigned, f);
  u += 0x7fffu + ((u >> 16) & 1u);   // round-to-nearest-even
  return (unsigned short)(u >> 16);
}
__device__ __forceinline__ float bf2f(unsigned short s) {
  unsigned u = (unsigned)s << 16;
  return __builtin_bit_cast(float, u);
}
__device__ __forceinline__ unsigned short f2h(float f) {
  __half h = __float2half(f);
  return __builtin_bit_cast(unsigned short, h);
}
__device__ __forceinline__ float h2f(unsigned short bits) {
  __half h = __builtin_bit_cast(__half, bits);
  return __half2float(h);
}

// ---------------------------------------------------------------------------
// Kernel A: prep. blocks 0..511: x NCHW fp32 -> NHWC bf16.
// blocks 512..871: repack main_w -> wt[k][128][64], offset_w -> wot[k][32][64].
// ---------------------------------------------------------------------------
__global__ __launch_bounds__(256) void prep_all(
    const float* __restrict__ x, const float* __restrict__ mw,
    const float* __restrict__ ow, unsigned short* __restrict__ xt,
    unsigned short* __restrict__ wt, unsigned short* __restrict__ wot) {
  __shared__ float tile[64 * 129];
  int blk = blockIdx.x;
  int t = threadIdx.x;
  if (blk < 512) {
    const float* xrow = x + ((long)(blk >> 7) << 20) + ((blk & 127) << 7);
#pragma unroll
    for (int i = 0; i < 32; ++i) {
      int idx = t + (i << 8);          // c = idx>>7, w = idx&127
      tile[(idx >> 7) * 129 + (idx & 127)] =
          xrow[((long)(idx >> 7) << 14) + (idx & 127)];
    }
    __syncthreads();
    unsigned short* orow = xt + ((long)blk << 13);
#pragma unroll
    for (int i = 0; i < 32; ++i) {
      int idx = t + (i << 8);          // w = idx>>6, c = idx&63
      orow[idx] = f2bf(tile[(idx & 63) * 129 + (idx >> 6)]);
    }
  } else {
    int idx = (blk - 512) * 256 + t;   // 0..92159
    if (idx < 73728) {
      int c = idx & 63;
      int o = (idx >> 6) & 127;
      int k = idx >> 13;
      wt[idx] = f2bf(mw[o * 576 + c * 9 + k]);
    } else {
      int i2 = idx - 73728;
      int c = i2 & 63;
      int o = (i2 >> 6) & 31;
      int k = i2 >> 11;
      wot[i2] = (o < 18) ? f2bf(ow[o * 576 + c * 9 + k]) : (unsigned short)0;
    }
  }
}

// ---------------------------------------------------------------------------
// Kernel B: fused offset-conv + deformable conv, all MFMA.
// Block = 32-px tile x 128 out-ch, 4 waves, grid 2048 (8 blocks/CU).
// Phase 0: offsets for own 32 px via MFMA mini-GEMM (M=32pad,K=576,N=32),
//          one (m,n) fragment per wave -> offs_lds.
// Phase 1: sampling table wtab (9 taps x 32 px).
// Phase 2: per tap: shared bilinear gather -> vlds (double-buffered),
//          MFMA 16x16x32 bf16; wave = (o-half, px-half).
// LDS: 4.6K wtab + 9.2K vlds + 2.3K offs = 16.1 KB.
// ---------------------------------------------------------------------------
__global__ __launch_bounds__(256) void deform_fused(
    const unsigned short* __restrict__ xt, const unsigned short* __restrict__ wt,
    const unsigned short* __restrict__ wot, const float* __restrict__ ob,
    const float* __restrict__ mb, float* __restrict__ out) {
  __shared__ uint4 wtab[9][32];
  __shared__ unsigned short vlds[2][32 * 72];
  __shared__ float offs_lds[18][32];

  int l = blockIdx.x;
  int bid = ((l & 7) << 8) + (l >> 3);   // XCD swizzle: 256 consecutive bids/XCD
  int tile = bid & 3;
  int h = (bid >> 2) & 127;
  int b = bid >> 9;
  int w0 = tile << 5;
  int t = threadIdx.x;
  int lane = t & 63;
  int wv = t >> 6;
  int l15 = lane & 15;
  int l4 = lane >> 4;                    // 0..3
  int l4k = l4 << 3;

  const unsigned short* xb = xt + ((long)b << 20);

  // ---- Phase 0: offset mini-GEMM. wave wv -> (m-frag wv>>1, n-frag wv&1) ----
  {
    int mf = wv >> 1;
    int nf = wv & 1;
    f32x4 oacc = f32x4{0.f, 0.f, 0.f, 0.f};
#pragma unroll 1
    for (int k = 0; k < 9; ++k) {
      int ky = k / 3, kx = k - 3 * ky;
      int y = h + ky - 1;
      bool yok = (unsigned)y < 128u;
      int yc = min(max(y, 0), 127);
      const unsigned short* xrow = xb + ((long)yc << 13);
      int px = w0 + (nf << 4) + l15 + kx - 1;
      bool pv = yok && ((unsigned)px < 128u);
      int pxo = min(max(px, 0), 127) << 6;
      const unsigned short* wk = wot + (((k << 5) + (mf << 4) + l15) << 6) + l4k;
#pragma unroll
      for (int c0 = 0; c0 < 64; c0 += 32) {
        bf16x8 af = *(const bf16x8*)(wk + c0);
        bf16x8 bv = *(const bf16x8*)(xrow + pxo + c0 + l4k);
        if (!pv) bv = bf16x8{0, 0, 0, 0, 0, 0, 0, 0};
        oacc = __builtin_amdgcn_mfma_f32_16x16x32_bf16(af, bv, oacc, 0, 0, 0);
      }
    }
#pragma unroll
    for (int r = 0; r < 4; ++r) {
      int oc = (mf << 4) + (l4 << 2) + r;
      if (oc < 18)
        offs_lds[oc][(nf << 4) + l15] = oacc[r] + ob[oc];
    }
  }
  __syncthreads();   // offs_lds ready

  // ---- Phase 1: sampling table (288 = 9 taps x 32 px) ----
  for (int idx = t; idx < 288; idx += 256) {
    int px = idx & 31, k = idx >> 5;
    int ky = k / 3, kx = k - 3 * ky;
    float dy = offs_lds[2 * k][px];
    float dx = offs_lds[2 * k + 1][px];
    float py = (float)(h - 1 + ky) + dy;
    float pxf = (float)(w0 + px - 1 + kx) + dx;
    float fy = floorf(py), fx = floorf(pxf);
    float wy = py - fy, wx = pxf - fx;
    int y0 = (int)fy, x0 = (int)fx;
    int y1 = y0 + 1, x1 = x0 + 1;
    bool vy0 = (unsigned)y0 < 128u, vy1 = (unsigned)y1 < 128u;
    bool vx0 = (unsigned)x0 < 128u, vx1 = (unsigned)x1 < 128u;
    float w00 = (vy0 && vx0) ? (1.f - wy) * (1.f - wx) : 0.f;
    float w01 = (vy0 && vx1) ? (1.f - wy) * wx : 0.f;
    float w10 = (vy1 && vx0) ? wy * (1.f - wx) : 0.f;
    float w11 = (vy1 && vx1) ? wy * wx : 0.f;
    int y0c = min(max(y0, 0), 127), y1c = min(max(y1, 0), 127);
    int x0c = min(max(x0, 0), 127), x1c = min(max(x1, 0), 127);
    wtab[k][px] = make_uint4(
        (unsigned)f2h(w00) | ((unsigned)f2h(w01) << 16),
        (unsigned)f2h(w10) | ((unsigned)f2h(w11) << 16),
        (unsigned)(unsigned short)y0c | ((unsigned)(unsigned short)y1c << 16),
        (unsigned)(unsigned short)x0c | ((unsigned)(unsigned short)x1c << 16));
  }

  // mfma identity for phase 2
  int wo = (wv & 1) << 6;                // o base: 0 / 64
  int wp = (wv >> 1) << 4;               // px base: 0 / 16

  f32x4 acc[4];
#pragma unroll
  for (int m = 0; m < 4; ++m) acc[m] = f32x4{0.f, 0.f, 0.f, 0.f};

  // one gather unit per thread: px = t>>3, c-chunk = t&7
  int spx = t >> 3;
  int sco = (t & 7) << 3;
  auto sample = [&](int k, unsigned short* buf) {
    uint4 e = wtab[k][spx];
    float w00 = h2f((unsigned short)(e.x & 0xffff));
    float w01 = h2f((unsigned short)(e.x >> 16));
    float w10 = h2f((unsigned short)(e.y & 0xffff));
    float w11 = h2f((unsigned short)(e.y >> 16));
    int y0 = (int)(short)(e.z & 0xffff), y1 = (int)(short)(e.z >> 16);
    int x0 = (int)(short)(e.w & 0xffff), x1 = (int)(short)(e.w >> 16);
    const unsigned short* r0 = xb + (y0 << 13) + sco;
    const unsigned short* r1 = xb + (y1 << 13) + sco;
    bf16x8 a00 = *(const bf16x8*)(r0 + (x0 << 6));
    bf16x8 a01 = *(const bf16x8*)(r0 + (x1 << 6));
    bf16x8 a10 = *(const bf16x8*)(r1 + (x0 << 6));
    bf16x8 a11 = *(const bf16x8*)(r1 + (x1 << 6));
    unsigned rr[4];
#pragma unroll
    for (int j = 0; j < 4; ++j) {
      float v0 = w00 * bf2f((unsigned short)a00[2 * j]) +
                 w01 * bf2f((unsigned short)a01[2 * j]) +
                 w10 * bf2f((unsigned short)a10[2 * j]) +
                 w11 * bf2f((unsigned short)a11[2 * j]);
      float v1 = w00 * bf2f((unsigned short)a00[2 * j + 1]) +
                 w01 * bf2f((unsigned short)a01[2 * j + 1]) +
                 w10 * bf2f((unsigned short)a10[2 * j + 1]) +
                 w11 * bf2f((unsigned short)a11[2 * j + 1]);
      rr[j] = (unsigned)f2bf(v0) | ((unsigned)f2bf(v1) << 16);
    }
    *(uint4*)&buf[spx * 72 + sco] = make_uint4(rr[0], rr[1], rr[2], rr[3]);
  };

  __syncthreads();          // wtab ready
  sample(0, vlds[0]);
  __syncthreads();          // buf0 ready

#pragma unroll 1
  for (int k = 0; k < 9; ++k) {
    const unsigned short* buf = vlds[k & 1];
    if (k < 8) sample(k + 1, vlds[(k + 1) & 1]);   // overlap with MFMA below

    const unsigned short* wk = wt + (((k << 7) + wo + l15) << 6) + l4k;
#pragma unroll
    for (int c0 = 0; c0 < 64; c0 += 32) {
      bf16x8 af[4];
#pragma unroll
      for (int m = 0; m < 4; ++m)
        af[m] = *(const bf16x8*)(wk + c0 + (m << 10));
      bf16x8 bfr = *(const bf16x8*)&buf[(wp + l15) * 72 + c0 + l4k];
#pragma unroll
      for (int m = 0; m < 4; ++m)
        acc[m] = __builtin_amdgcn_mfma_f32_16x16x32_bf16(af[m], bfr, acc[m], 0, 0, 0);
    }
    __syncthreads();        // buffer consumed / next ready
  }

  // ---- epilogue: D row = o (lane>>4)*4+reg, col = px (lane&15) ----
  int hw0 = (h << 7) + w0;
#pragma unroll
  for (int m = 0; m < 4; ++m) {
    int orow = wo + (m << 4) + (l4 << 2);
#pragma unroll
    for (int r = 0; r < 4; ++r)
      out[((long)(b * 128 + orow + r) << 14) + hw0 + wp + l15] =
          acc[m][r] + mb[orow + r];
  }
}

extern "C" void kernel_launch(void* const* d_in, const int* in_sizes, int n_in,
                              void* d_out, int out_size, void* d_ws, size_t ws_size,
                              hipStream_t stream) {
  const float* x  = (const float*)d_in[0];
  const float* ow = (const float*)d_in[1];
  const float* ob = (const float*)d_in[2];
  const float* mw = (const float*)d_in[3];
  const float* mb = (const float*)d_in[4];
  float* out  = (float*)d_out;
  unsigned short* xt  = (unsigned short*)d_ws;                      // 8 MB
  unsigned short* wt  = (unsigned short*)((char*)d_ws + 8388608);   // 144 KB
  unsigned short* wot = (unsigned short*)((char*)d_ws + 8536064);   // 36 KB

  prep_all<<<872, 256, 0, stream>>>(x, mw, ow, xt, wt, wot);
  deform_fused<<<2048, 256, 0, stream>>>(xt, wt, wot, ob, mb, out);
}

// Round 7
// 71.541 us; speedup vs baseline: 1.8885x; 1.8767x over previous
//
#include <hip/hip_runtime.h>
#include <hip/hip_fp16.h>

typedef __attribute__((ext_vector_type(8))) short bf16x8;
typedef __attribute__((ext_vector_type(4))) float f32x4;

__device__ __forceinline__ unsigned short f2bf(float f) {
  unsigned u = __builtin_bit_cast(unsigned, f);
  u += 0x7fffu + ((u >> 16) & 1u);   // round-to-nearest-even
  return (unsigned short)(u >> 16);
}
__device__ __forceinline__ float bf2f(unsigned short s) {
  unsigned u = (unsigned)s << 16;
  return __builtin_bit_cast(float, u);
}
__device__ __forceinline__ unsigned short f2h(float f) {
  __half h = __float2half(f);
  return __builtin_bit_cast(unsigned short, h);
}
__device__ __forceinline__ float h2f(unsigned short bits) {
  __half h = __builtin_bit_cast(__half, bits);
  return __half2float(h);
}

// ---------------------------------------------------------------------------
// Kernel A: prep. blocks 0..511: x NCHW fp32 -> NHWC bf16 xt[b][h][w][c].
// blocks 512..871: repack main_w -> wt[k][128][64], offset_w -> wot[k][32][64].
// ---------------------------------------------------------------------------
__global__ __launch_bounds__(256) void prep_all(
    const float* __restrict__ x, const float* __restrict__ mw,
    const float* __restrict__ ow, unsigned short* __restrict__ xt,
    unsigned short* __restrict__ wt, unsigned short* __restrict__ wot) {
  __shared__ float tile[64 * 129];
  int blk = blockIdx.x;
  int t = threadIdx.x;
  if (blk < 512) {
    const float* xrow = x + ((long)(blk >> 7) << 20) + ((blk & 127) << 7);
#pragma unroll
    for (int i = 0; i < 32; ++i) {
      int idx = t + (i << 8);          // c = idx>>7, w = idx&127
      tile[(idx >> 7) * 129 + (idx & 127)] =
          xrow[((long)(idx >> 7) << 14) + (idx & 127)];
    }
    __syncthreads();
    unsigned short* orow = xt + ((long)blk << 13);
#pragma unroll
    for (int i = 0; i < 32; ++i) {
      int idx = t + (i << 8);          // w = idx>>6, c = idx&63
      orow[idx] = f2bf(tile[(idx & 63) * 129 + (idx >> 6)]);
    }
  } else {
    int idx = (blk - 512) * 256 + t;   // 0..92159
    if (idx < 73728) {
      int c = idx & 63;
      int o = (idx >> 6) & 127;
      int k = idx >> 13;
      wt[idx] = f2bf(mw[o * 576 + c * 9 + k]);
    } else {
      int i2 = idx - 73728;
      int c = i2 & 63;
      int o = (i2 >> 6) & 31;
      int k = i2 >> 11;
      wot[i2] = (o < 18) ? f2bf(ow[o * 576 + c * 9 + k]) : (unsigned short)0;
    }
  }
}

// ---------------------------------------------------------------------------
// Kernel B: offset conv 64->18 via MFMA. Block = 64-px half-row, 4 waves;
// wave wv -> 16-px column (n=1 frag), 2 m-frags (o rows 0..31, 18 used).
// B-frags straight from xt (L2-hot, clamp+mask). No LDS, no barriers.
// Grid 1024, XCD-swizzled.
// ---------------------------------------------------------------------------
__global__ __launch_bounds__(256) void offs_mfma(
    const unsigned short* __restrict__ xt, const unsigned short* __restrict__ wot,
    const float* __restrict__ ob, float* __restrict__ offs) {
  int l = blockIdx.x;
  int bid = ((l & 7) << 7) + (l >> 3);   // XCD swizzle: 128 consecutive bids/XCD
  int b = bid >> 8;
  int r8 = bid & 255;
  int h = r8 >> 1;
  int w0 = (r8 & 1) << 6;
  int t = threadIdx.x;
  int lane = t & 63;
  int wv = t >> 6;
  int l15 = lane & 15;
  int l4 = lane >> 4;
  int l4k = l4 << 3;

  f32x4 oacc[2];
  oacc[0] = f32x4{0.f, 0.f, 0.f, 0.f};
  oacc[1] = f32x4{0.f, 0.f, 0.f, 0.f};

  const unsigned short* xb = xt + ((long)b << 20);
  const unsigned short* wkb = wot + (l15 << 6) + l4k;

#pragma unroll 1
  for (int k = 0; k < 9; ++k) {
    int ky = k / 3, kx = k - 3 * ky;
    int y = h + ky - 1;
    bool yok = (unsigned)y < 128u;
    int yc = min(max(y, 0), 127);
    const unsigned short* xrow = xb + ((long)yc << 13);
    int px = w0 + (wv << 4) + l15 + kx - 1;
    bool pv = yok && ((unsigned)px < 128u);
    int pxo = min(max(px, 0), 127) << 6;
#pragma unroll
    for (int c0 = 0; c0 < 64; c0 += 32) {
      bf16x8 bv = *(const bf16x8*)(xrow + pxo + c0 + l4k);
      if (!pv) bv = bf16x8{0, 0, 0, 0, 0, 0, 0, 0};
#pragma unroll
      for (int m = 0; m < 2; ++m) {
        bf16x8 af = *(const bf16x8*)(wkb + (k << 11) + (m << 10) + c0);
        oacc[m] = __builtin_amdgcn_mfma_f32_16x16x32_bf16(af, bv, oacc[m], 0, 0, 0);
      }
    }
  }

#pragma unroll
  for (int m = 0; m < 2; ++m) {
#pragma unroll
    for (int r = 0; r < 4; ++r) {
      int oc = (m << 4) + (l4 << 2) + r;
      if (oc < 18)
        offs[((long)(b * 18 + oc) << 14) + (h << 7) + w0 + (wv << 4) + l15] =
            oacc[m][r] + ob[oc];
    }
  }
}

// ---------------------------------------------------------------------------
// Kernel C: deformable conv via MFMA, NHWC-bf16 gather.
// Block = 64-px half-row x 128 out-ch, 4 waves, grid 1024, XCD-swizzled.
// Wave wv owns DISJOINT o-quarter (wo = wv*32, 2 m-frags) x all 64 px
// (4 n-frags) -> zero wt duplication across waves (halves wt L2 traffic).
// Double-buffered V tile; sample tap k+1 while MFMA consumes tap k.
// LDS: 9.2K wtab + 2x9.2K vlds = 27.6 KB -> 5 blocks/CU.
// ---------------------------------------------------------------------------
__global__ __launch_bounds__(256) void deform_mfma(
    const unsigned short* __restrict__ xt, const float* __restrict__ offs,
    const unsigned short* __restrict__ wt, const float* __restrict__ mb,
    float* __restrict__ out) {
  __shared__ uint4 wtab[9][64];
  __shared__ unsigned short vlds[2][64 * 72];

  int l = blockIdx.x;
  int bid = ((l & 7) << 7) + (l >> 3);   // XCD swizzle: 128 consecutive bids/XCD
  int b = bid >> 8;
  int r8 = bid & 255;
  int h = r8 >> 1;
  int w0 = (r8 & 1) << 6;
  int t = threadIdx.x;
  int lane = t & 63;
  int wv = t >> 6;
  int wo = wv << 5;                      // disjoint o-quarter per wave
  int l15 = lane & 15;
  int l4 = lane >> 4;
  int l4k = l4 << 3;

  // ---- sampling table: 576 = 9 taps x 64 px ----
  const float* ob_ = offs + ((long)(b * 18) << 14) + (h << 7) + w0;
  for (int idx = t; idx < 576; idx += 256) {
    int px = idx & 63, k = idx >> 6;
    int ky = k / 3, kx = k - 3 * ky;
    float dy = ob_[((2 * k) << 14) + px];
    float dx = ob_[((2 * k + 1) << 14) + px];
    float py = (float)(h - 1 + ky) + dy;
    float pxf = (float)(w0 + px - 1 + kx) + dx;
    float fy = floorf(py), fx = floorf(pxf);
    float wy = py - fy, wx = pxf - fx;
    int y0 = (int)fy, x0 = (int)fx;
    int y1 = y0 + 1, x1 = x0 + 1;
    bool vy0 = (unsigned)y0 < 128u, vy1 = (unsigned)y1 < 128u;
    bool vx0 = (unsigned)x0 < 128u, vx1 = (unsigned)x1 < 128u;
    float w00 = (vy0 && vx0) ? (1.f - wy) * (1.f - wx) : 0.f;
    float w01 = (vy0 && vx1) ? (1.f - wy) * wx : 0.f;
    float w10 = (vy1 && vx0) ? wy * (1.f - wx) : 0.f;
    float w11 = (vy1 && vx1) ? wy * wx : 0.f;
    int y0c = min(max(y0, 0), 127), y1c = min(max(y1, 0), 127);
    int x0c = min(max(x0, 0), 127), x1c = min(max(x1, 0), 127);
    wtab[k][px] = make_uint4(
        (unsigned)f2h(w00) | ((unsigned)f2h(w01) << 16),
        (unsigned)f2h(w10) | ((unsigned)f2h(w11) << 16),
        (unsigned)(unsigned short)y0c | ((unsigned)(unsigned short)y1c << 16),
        (unsigned)(unsigned short)x0c | ((unsigned)(unsigned short)x1c << 16));
  }

  f32x4 acc[2][4];
#pragma unroll
  for (int m = 0; m < 2; ++m)
#pragma unroll
    for (int n = 0; n < 4; ++n) acc[m][n] = f32x4{0.f, 0.f, 0.f, 0.f};

  const unsigned short* xb = xt + ((long)b << 20);

  // sample tap k into buf: 512 units = 64 px x 8 c-chunks, 2 per thread
  auto sample = [&](int k, unsigned short* buf) {
#pragma unroll
    for (int it = 0; it < 2; ++it) {
      int idx2 = t + (it << 8);
      int px = idx2 >> 3, chunk = idx2 & 7;
      uint4 e = wtab[k][px];
      float w00 = h2f((unsigned short)(e.x & 0xffff));
      float w01 = h2f((unsigned short)(e.x >> 16));
      float w10 = h2f((unsigned short)(e.y & 0xffff));
      float w11 = h2f((unsigned short)(e.y >> 16));
      int y0 = (int)(short)(e.z & 0xffff), y1 = (int)(short)(e.z >> 16);
      int x0 = (int)(short)(e.w & 0xffff), x1 = (int)(short)(e.w >> 16);
      int co = chunk << 3;
      const unsigned short* r0 = xb + (y0 << 13) + co;
      const unsigned short* r1 = xb + (y1 << 13) + co;
      bf16x8 a00 = *(const bf16x8*)(r0 + (x0 << 6));
      bf16x8 a01 = *(const bf16x8*)(r0 + (x1 << 6));
      bf16x8 a10 = *(const bf16x8*)(r1 + (x0 << 6));
      bf16x8 a11 = *(const bf16x8*)(r1 + (x1 << 6));
      unsigned rr[4];
#pragma unroll
      for (int j = 0; j < 4; ++j) {
        float v0 = w00 * bf2f((unsigned short)a00[2 * j]) +
                   w01 * bf2f((unsigned short)a01[2 * j]) +
                   w10 * bf2f((unsigned short)a10[2 * j]) +
                   w11 * bf2f((unsigned short)a11[2 * j]);
        float v1 = w00 * bf2f((unsigned short)a00[2 * j + 1]) +
                   w01 * bf2f((unsigned short)a01[2 * j + 1]) +
                   w10 * bf2f((unsigned short)a10[2 * j + 1]) +
                   w11 * bf2f((unsigned short)a11[2 * j + 1]);
        rr[j] = (unsigned)f2bf(v0) | ((unsigned)f2bf(v1) << 16);
      }
      *(uint4*)&buf[px * 72 + co] = make_uint4(rr[0], rr[1], rr[2], rr[3]);
    }
  };

  __syncthreads();          // wtab ready
  sample(0, vlds[0]);
  __syncthreads();          // buf0 ready

  const unsigned short* wkb = wt + ((wo + l15) << 6) + l4k;

#pragma unroll 1
  for (int k = 0; k < 9; ++k) {
    const unsigned short* buf = vlds[k & 1];
    if (k < 8) sample(k + 1, vlds[(k + 1) & 1]);   // overlap with MFMA below

#pragma unroll
    for (int c0 = 0; c0 < 64; c0 += 32) {
      bf16x8 af[2], bfr[4];
#pragma unroll
      for (int m = 0; m < 2; ++m)
        af[m] = *(const bf16x8*)(wkb + (k << 13) + (m << 10) + c0);
#pragma unroll
      for (int n = 0; n < 4; ++n)
        bfr[n] = *(const bf16x8*)&buf[((n << 4) + l15) * 72 + c0 + l4k];
#pragma unroll
      for (int m = 0; m < 2; ++m)
#pragma unroll
        for (int n = 0; n < 4; ++n)
          acc[m][n] = __builtin_amdgcn_mfma_f32_16x16x32_bf16(
              af[m], bfr[n], acc[m][n], 0, 0, 0);
    }
    __syncthreads();        // buffer consumed / next ready
  }

  // ---- epilogue: D row = o (lane>>4)*4+reg, col = px (lane&15) ----
  int hw0 = (h << 7) + w0;
#pragma unroll
  for (int m = 0; m < 2; ++m) {
    int orow = wo + (m << 4) + (l4 << 2);
#pragma unroll
    for (int r = 0; r < 4; ++r) {
      float bias = mb[orow + r];
      long ob2 = ((long)(b * 128 + orow + r) << 14) + hw0;
#pragma unroll
      for (int n = 0; n < 4; ++n)
        out[ob2 + (n << 4) + l15] = acc[m][n][r] + bias;
    }
  }
}

extern "C" void kernel_launch(void* const* d_in, const int* in_sizes, int n_in,
                              void* d_out, int out_size, void* d_ws, size_t ws_size,
                              hipStream_t stream) {
  const float* x  = (const float*)d_in[0];
  const float* ow = (const float*)d_in[1];
  const float* ob = (const float*)d_in[2];
  const float* mw = (const float*)d_in[3];
  const float* mb = (const float*)d_in[4];
  float* out  = (float*)d_out;
  unsigned short* xt  = (unsigned short*)d_ws;                      // 8 MB
  unsigned short* wt  = (unsigned short*)((char*)d_ws + 8388608);   // 144 KB
  unsigned short* wot = (unsigned short*)((char*)d_ws + 8536064);   // 36 KB
  float* offs = (float*)((char*)d_ws + 8572928);                    // 4.5 MB

  prep_all<<<872, 256, 0, stream>>>(x, mw, ow, xt, wt, wot);
  offs_mfma<<<1024, 256, 0, stream>>>(xt, wot, ob, offs);
  deform_mfma<<<1024, 256, 0, stream>>>(xt, offs, wt, mb, out);
}